// Round 1
// 247.660 us; speedup vs baseline: 1.0235x; 1.0235x over previous
//
#include <hip/hip_runtime.h>
#include <stdint.h>

// Lovasz-softmax loss without sorting:
//   loss_c = sum over descending error levels v of v * (J(n>=v, f>=v) - J_prev)
// where n(v)=#{err_c >= v}, f(v)=#{label==c and err_c >= v},
//   J(n,f) = 1 - (G - f) / (G + n - f), G = #{label==c}.
// Tie-grouping is exact; quantizing errors to 768 bins perturbs loss by
// <= 2 * 0.5/767 ~= 1.3e-3 (threshold is 1.9e-2).
//
// R1 changes vs baseline (theory: dur includes ~186us of harness workspace
// poison fills; our kernels are ~67us of the 253us -> shrink them):
//  - k1: 4 px/thread, float4/int4 loads (VMEM instrs /4, addr VALU /4)
//  - 256 blocks (halves flush 30->15 MB and k2 read)
//  - rcp + fused 767/s scale in binning
//  - k4 merged into k3 via agent-scope ticket (one fewer launch)

#define C_CLASSES 19
#define NBINS 768
#define HISTWORDS (C_CLASSES * NBINS)   // 14592 = 57*256
#define HW_SHIFT 18                     // H*W = 512*512 = 2^18
#define HW_MASK ((1 << HW_SHIFT) - 1)
#define NGROUPS 8

// Per-pixel softmax-error binning. r[] holds logits minus nothing; m is the max.
// On exit r[] is clobbered (holds exp values). Packed LDS counters:
// low 16 bits = n count, high 16 bits = fg count (per-block counts < 2^16).
__device__ __forceinline__ void px_process(float* r, float m, int lab,
                                           unsigned int* hist)
{
    float s = 0.f;
#pragma unroll
    for (int c = 0; c < C_CLASSES; ++c) {
        float t = __expf(r[c] - m);
        r[c] = t;
        s += t;
    }
    // scale = 767 / sum; bin for non-fg is rn(767*pr), fg is 767 - rn(767*pr)
    // (differs from rn(767*(1-pr)) by at most 1 bin on ties; loss delta ~1e-5)
    float scale = (float)(NBINS - 1) * __builtin_amdgcn_rcpf(s);
#pragma unroll
    for (int c = 0; c < C_CLASSES; ++c) {
        int ti = __float2int_rn(r[c] * scale);
        int idx = (c == lab) ? (NBINS - 1 - ti) : ti;
        idx = idx < 0 ? 0 : (idx > NBINS - 1 ? NBINS - 1 : idx);
        atomicAdd(&hist[c * NBINS + idx], (c == lab) ? 0x10001u : 1u);
    }
}

// K1: fused softmax + error histogram, 4 pixels per thread per iteration.
__global__ __launch_bounds__(1024) void k1_hist(
    const float* __restrict__ x, const int* __restrict__ labels,
    unsigned int* __restrict__ copies, int P, int pixPerBlk)
{
    __shared__ unsigned int hist[HISTWORDS];   // 58368 B
    int tid = threadIdx.x;
    uint4* h4 = (uint4*)hist;
    for (int i = tid; i < HISTWORDS / 4; i += 1024) h4[i] = make_uint4(0u, 0u, 0u, 0u);
    __syncthreads();

    int base = blockIdx.x * pixPerBlk;
    for (int it = 0; it < pixPerBlk; it += 4096) {
        int pix = base + it + tid * 4;          // pix % 4 == 0 always
        if (pix + 3 < P) {
            // 4 consecutive pixels never cross an image boundary (2^18 | 4)
            int img = pix >> HW_SHIFT;
            int rem = pix & HW_MASK;
            const float* xp = x + (((size_t)img * C_CLASSES) << HW_SHIFT) + rem;
            float r0[C_CLASSES], r1[C_CLASSES], r2[C_CLASSES], r3[C_CLASSES];
            float m0 = -3.4e38f, m1 = -3.4e38f, m2 = -3.4e38f, m3 = -3.4e38f;
#pragma unroll
            for (int c = 0; c < C_CLASSES; ++c) {
                float4 v = *reinterpret_cast<const float4*>(xp + ((size_t)c << HW_SHIFT));
                r0[c] = v.x; r1[c] = v.y; r2[c] = v.z; r3[c] = v.w;
                m0 = fmaxf(m0, v.x); m1 = fmaxf(m1, v.y);
                m2 = fmaxf(m2, v.z); m3 = fmaxf(m3, v.w);
            }
            int4 lb = *reinterpret_cast<const int4*>(labels + pix);
            px_process(r0, m0, lb.x, hist);
            px_process(r1, m1, lb.y, hist);
            px_process(r2, m2, lb.z, hist);
            px_process(r3, m3, lb.w, hist);
        } else {
#pragma unroll
            for (int k = 0; k < 4; ++k) {
                int p = pix + k;
                if (p < P) {
                    int img = p >> HW_SHIFT;
                    int rem = p & HW_MASK;
                    const float* xp = x + (((size_t)img * C_CLASSES) << HW_SHIFT) + rem;
                    float r[C_CLASSES];
                    float m = -3.4e38f;
#pragma unroll
                    for (int c = 0; c < C_CLASSES; ++c) {
                        r[c] = xp[(size_t)c << HW_SHIFT];
                        m = fmaxf(m, r[c]);
                    }
                    px_process(r, m, labels[p], hist);
                }
            }
        }
    }
    __syncthreads();
    // plain-store flush to this block's private copy (no global atomics)
    uint4* dst = (uint4*)(copies + (size_t)blockIdx.x * HISTWORDS);
    const uint4* src = (const uint4*)hist;
    for (int i = tid; i < HISTWORDS / 4; i += 1024) dst[i] = src[i];
}

// K2: reduce ncopies private histograms into NGROUPS partial (n,f) histograms.
// Also re-inits the k3 completion ticket (workspace is poisoned between runs).
__global__ __launch_bounds__(256) void k2_reduce(
    const unsigned int* __restrict__ copies,
    int* __restrict__ nPart, int* __restrict__ fPart,
    int* __restrict__ ticket, int ncopies, int cpg)
{
    if (blockIdx.x == 0 && blockIdx.y == 0 && threadIdx.x == 0) *ticket = 0;
    int pos = blockIdx.x * 256 + threadIdx.x;   // 0..HISTWORDS-1 (grid.x = 57)
    int g = blockIdx.y;
    int c0 = g * cpg;
    int c1 = c0 + cpg; if (c1 > ncopies) c1 = ncopies;
    unsigned int sn = 0, sf = 0;
    for (int k = c0; k < c1; ++k) {
        unsigned int w = copies[(size_t)k * HISTWORDS + pos];
        sn += w & 0xFFFFu;
        sf += w >> 16;
    }
    nPart[(size_t)g * HISTWORDS + pos] = (int)sn;
    fPart[(size_t)g * HISTWORDS + pos] = (int)sf;
}

// K3: one wave per class — descending-bin prefix scan + Jaccard integral.
// Last block to finish also averages over present classes (former k4).
__global__ __launch_bounds__(64) void k3_scan(
    const int* __restrict__ nPart, const int* __restrict__ fPart,
    float* __restrict__ res, int* __restrict__ ticket,
    float* __restrict__ out)
{
    int c = blockIdx.x;
    int lane = threadIdx.x;
    const int PER = NBINS / 64;   // 12
    int nl[PER], fl[PER];
    int totN = 0, totF = 0;
#pragma unroll
    for (int i = 0; i < PER; ++i) {
        int j = lane * PER + i;            // ascending j = descending error value
        int bin = NBINS - 1 - j;
        int pos = c * NBINS + bin;
        int n = 0, f = 0;
#pragma unroll
        for (int g = 0; g < NGROUPS; ++g) {
            n += nPart[g * HISTWORDS + pos];
            f += fPart[g * HISTWORDS + pos];
        }
        nl[i] = n; fl[i] = f; totN += n; totF += f;
    }
    // inclusive scan of lane totals across the wave
    int incN = totN, incF = totF;
    for (int off = 1; off < 64; off <<= 1) {
        int tn = __shfl_up(incN, off);
        int tf = __shfl_up(incF, off);
        if (lane >= off) { incN += tn; incF += tf; }
    }
    int G = __shfl(incF, 63);
    double loss = 0.0;
    if (G > 0) {
        int cumN = incN - totN;            // exclusive prefix for this lane
        int cumF = incF - totF;
        double dG = (double)G;
        double Jb = 1.0 - (dG - (double)cumF) / (dG + (double)cumN - (double)cumF);
#pragma unroll
        for (int i = 0; i < PER; ++i) {
            int bin = NBINS - 1 - (lane * PER + i);
            cumN += nl[i]; cumF += fl[i];
            double Ja = 1.0 - (dG - (double)cumF) / (dG + (double)cumN - (double)cumF);
            loss += ((double)bin / (double)(NBINS - 1)) * (Ja - Jb);
            Jb = Ja;
        }
    }
    for (int off = 32; off > 0; off >>= 1)
        loss += __shfl_down(loss, off);
    if (lane == 0) {
        __hip_atomic_store(&res[c], (float)loss, __ATOMIC_RELAXED, __HIP_MEMORY_SCOPE_AGENT);
        __hip_atomic_store(&res[C_CLASSES + c], (float)G, __ATOMIC_RELAXED, __HIP_MEMORY_SCOPE_AGENT);
        int t = __hip_atomic_fetch_add(ticket, 1, __ATOMIC_ACQ_REL, __HIP_MEMORY_SCOPE_AGENT);
        if (t == C_CLASSES - 1) {
            float s = 0.f, cnt = 0.f;
            for (int cc = 0; cc < C_CLASSES; ++cc) {
                float g = __hip_atomic_load(&res[C_CLASSES + cc], __ATOMIC_RELAXED, __HIP_MEMORY_SCOPE_AGENT);
                if (g > 0.f) {
                    s += __hip_atomic_load(&res[cc], __ATOMIC_RELAXED, __HIP_MEMORY_SCOPE_AGENT);
                    cnt += 1.f;
                }
            }
            out[0] = s / fmaxf(cnt, 1.f);
        }
    }
}

extern "C" void kernel_launch(void* const* d_in, const int* in_sizes, int n_in,
                              void* d_out, int out_size, void* d_ws, size_t ws_size,
                              hipStream_t stream)
{
    const float* x = (const float*)d_in[0];
    const int* labels = (const int*)d_in[1];
    float* out = (float*)d_out;
    int P = in_sizes[1];   // B*H*W = 2,097,152

    const size_t histBytes = (size_t)HISTWORDS * 4;           // 58,368
    const size_t partBytes = (size_t)NGROUPS * HISTWORDS * 4; // 466,944
    const size_t resBytes = 256;                              // res[38] + ticket
    const size_t reserved = 2 * partBytes + resBytes + 256;

    int maxCopies = (int)((ws_size > reserved ? ws_size - reserved : 0) / histBytes);
    int ncopies = maxCopies < 256 ? maxCopies : 256;
    if (ncopies < 1) ncopies = 1;
    int pixPerBlk = (P + ncopies - 1) / ncopies;
    pixPerBlk = ((pixPerBlk + 4095) / 4096) * 4096;           // multiple of 1024 threads * 4 px

    unsigned int* copies = (unsigned int*)d_ws;
    int* nPart = (int*)((char*)d_ws + histBytes * (size_t)ncopies);
    int* fPart = (int*)((char*)nPart + partBytes);
    float* res = (float*)((char*)fPart + partBytes);
    int* ticket = (int*)((char*)res + 160);

    int cpg = (ncopies + NGROUPS - 1) / NGROUPS;

    k1_hist<<<dim3(ncopies), dim3(1024), 0, stream>>>(x, labels, copies, P, pixPerBlk);
    k2_reduce<<<dim3(HISTWORDS / 256, NGROUPS), dim3(256), 0, stream>>>(copies, nPart, fPart, ticket, ncopies, cpg);
    k3_scan<<<dim3(C_CLASSES), dim3(64), 0, stream>>>(nPart, fPart, res, ticket, out);
}